// Round 7
// baseline (40563.913 us; speedup 1.0000x reference)
//
#include <hip/hip_runtime.h>
#include <hip/hip_bf16.h>

// Problem constants (S,B,D,H,T) = (4,512,256,1024,50)
#define S_ 4
#define B_ 512
#define D_ 256
#define H_ 1024
#define T_ 50
#define M_ (S_*B_)   // 2048 rows total

#define LDH (H_ + 8)   // padded LDS row stride for h1/h2 (bf16 elems)
#define LDU (D_ + 8)   // padded LDS row stride for u

// Per-block per-stage weight stream (pair-split):
//   [W1 half: chunks 0..15 | W2 half: 16..79 | W3 full: 80..111] = 112 x 16KB
#define NCHK 112
#define CHKB 16384

typedef __attribute__((ext_vector_type(8))) __bf16 bf16x8;
typedef __attribute__((ext_vector_type(4))) float  f32x4;

#define MFMA16(a, b, c) __builtin_amdgcn_mfma_f32_16x16x32_bf16(a, b, c, 0, 0, 0)
#define SB0() __builtin_amdgcn_sched_barrier(0)
// chunk-landed wait: 6 younger chunks (12 loads) may stay in flight
#define VMW() do { asm volatile("s_waitcnt vmcnt(12)" ::: "memory"); SB0(); } while (0)
// layer barrier WITHOUT vmcnt drain (register prefetch stays in flight)
#define LBAR() do { SB0(); asm volatile("s_waitcnt lgkmcnt(0)" ::: "memory"); \
                    __builtin_amdgcn_s_barrier(); SB0(); } while (0)

// Two B-fragments (one chunk's per-wave slice halves) global -> VGPR, direct
// in MFMA layout.
__device__ __forceinline__ void ld2(bf16x8& r0, bf16x8& r1, const void* p) {
  asm volatile("global_load_dwordx4 %0, %2, off\n\t"
               "global_load_dwordx4 %1, %2, off offset:1024"
               : "=&v"(r0), "=&v"(r1) : "v"(p) : "memory");
}

__device__ __forceinline__ void gld16(const void* g, void* l) {
  // async global->LDS, 16B/lane. LDS dest = wave-uniform base (+lane*16 by HW).
  __builtin_amdgcn_global_load_lds(
      (const __attribute__((address_space(1))) void*)g,
      (__attribute__((address_space(3))) void*)l, 16, 0, 0);
}

// NaN-free fast tanh
__device__ __forceinline__ float fast_tanh(float x) {
  const float e = __expf(2.f * x);
  return 1.f - 2.f / (e + 1.f);
}

__device__ __forceinline__ void store_out(void* out, size_t off, float v,
                                          int ofl) {
  if (ofl) {
    __builtin_nontemporal_store(v, (float*)out + off);
  } else {
    const unsigned short u =
        __builtin_bit_cast(unsigned short, __float2bfloat16(v));
    __builtin_nontemporal_store(u, (unsigned short*)out + off);
  }
}

// ---------------------------------------------------------------------------
// dtype detection + dt table + reg_state zeros + exchange-flag zeroing
// ---------------------------------------------------------------------------
__global__ void detect_k(const void* t_raw, const void* w2_raw,
                         float* dts, int* flags, void* out, int* xflag) {
  __shared__ int cnt;
  const int l = threadIdx.x;           // 64 threads, 1 block
  if (l == 0) cnt = 0;
  __syncthreads();
  const unsigned short* u = (const unsigned short*)w2_raw;
  int c = 0;
  #pragma unroll
  for (int j = 0; j < 4; ++j) {
    const unsigned short v = u[l * 4 + j];
    const unsigned e = (v >> 7) & 0xFF;
    if (e >= 128) c++;
  }
  atomicAdd(&cnt, c);
  __syncthreads();
  const unsigned tw0 = *(const unsigned*)t_raw;
  const int t_is_f32 = (tw0 == 0u) ? 1 : 0;
  const int w_is_f32 = (cnt > 16) ? 1 : 0;
  if (l == 0) { flags[0] = w_is_f32; flags[1] = t_is_f32; }
  for (int i = l; i < 256 * 16; i += 64) xflag[i] = 0;   // zero epoch flags
  if (l < T_ - 1) {
    float t0, t1;
    if (t_is_f32) {
      const float* tf = (const float*)t_raw;
      t0 = tf[l]; t1 = tf[l + 1];
    } else {
      const __hip_bfloat16* tb = (const __hip_bfloat16*)t_raw;
      t0 = __bfloat162float(tb[l]); t1 = __bfloat162float(tb[l + 1]);
    }
    dts[l] = t1 - t0;
  }
  if (l < S_) {   // reg_state = 0
    const size_t ro = (size_t)M_ * T_ * D_ + l;
    if (w_is_f32) ((float*)out)[ro] = 0.f;
    else          ((__hip_bfloat16*)out)[ro] = __float2bfloat16(0.f);
  }
}

// ---------------------------------------------------------------------------
// transpose to bf16: dst[N][K] = bf16(src[K][N])
// ---------------------------------------------------------------------------
__global__ void transpose_k(const void* __restrict__ src,
                            __hip_bfloat16* __restrict__ dst, int K, int N,
                            const int* __restrict__ flags) {
  __shared__ __hip_bfloat16 tile[32][33];
  const int f32 = flags[0];
  const int tx = threadIdx.x, ty = threadIdx.y;
  const int nb = blockIdx.x * 32, kb = blockIdx.y * 32;
  #pragma unroll
  for (int j = 0; j < 32; j += 8) {
    const size_t si = (size_t)(kb + ty + j) * N + nb + tx;
    tile[ty + j][tx] = f32 ? __float2bfloat16(((const float*)src)[si])
                           : ((const __hip_bfloat16*)src)[si];
  }
  __syncthreads();
  #pragma unroll
  for (int j = 0; j < 32; j += 8)
    dst[(size_t)(nb + ty + j) * K + kb + tx] = tile[tx][ty + j];
}

// ---------------------------------------------------------------------------
// biases -> fp32 workspace arrays
// ---------------------------------------------------------------------------
__global__ void prep_bias_k(const void* b1r, const void* b2r, const void* b3r,
                            float* bf1, float* bf2, float* bf3,
                            const int* flags) {
  const int i = blockIdx.x * 256 + threadIdx.x;   // H_ threads
  const int f32 = flags[0];
  bf1[i] = f32 ? ((const float*)b1r)[i]
               : __bfloat162float(((const __hip_bfloat16*)b1r)[i]);
  bf2[i] = f32 ? ((const float*)b2r)[i]
               : __bfloat162float(((const __hip_bfloat16*)b2r)[i]);
  if (i < D_)
    bf3[i] = f32 ? ((const float*)b3r)[i]
                 : __bfloat162float(((const __hip_bfloat16*)b3r)[i]);
}

// ---------------------------------------------------------------------------
// pack Wt[N][K] into 16KB-chunk wave-private fragment stream, with column
// offset coff and K-rotation krot (kk_eff = (kk + krot) mod KT).
// frag idx = c*1024 + w*128 + ntl*64 + lane, ntl in {0,1}:
//   TPW==4: chunk c -> kk0 = c>>1, nt = (c&1)*2 + ntl   (2 chunks per kk)
//   TPW==2: chunk c -> kk0 = c,    nt = ntl
// Fragment content (MFMA B layout), elems j of lane:
//   Wt[coff + (w*TPW+nt)*16 + (lane&15)][kk*32 + (lane>>4)*8 + j]
// ---------------------------------------------------------------------------
__global__ void pack2_k(const __hip_bfloat16* __restrict__ Wt,
                        __hip_bfloat16* __restrict__ P, int K, int TPW,
                        int coff, int krot) {
  const int frag = blockIdx.x * 256 + threadIdx.x;
  const int lane = frag & 63;
  const int c    = frag >> 10;
  const int q    = frag & 1023;
  const int w    = q >> 7;
  const int ntl  = (q >> 6) & 1;
  const int KT   = K >> 5;
  int kk0, nt;
  if (TPW == 4) { kk0 = c >> 1; nt = (c & 1) * 2 + ntl; }
  else          { kk0 = c;      nt = ntl; }
  int kk = kk0 + krot; if (kk >= KT) kk -= KT;
  const int n  = coff + (w * TPW + nt) * 16 + (lane & 15);
  const int ko = kk * 32 + (lane >> 4) * 8;
  *(bf16x8*)&P[(size_t)frag * 8] = *(const bf16x8*)&Wt[(size_t)n * K + ko];
}

// ---------------------------------------------------------------------------
// Persistent pair-split ODE kernel: 256 blocks (128 pairs x 2 halves),
// 512 threads. Pair shares 16 rows; half h computes cols [h*512,+512) of
// L1/L2 (streams its own 1.75MB packed stream) and FULL L3 (k duplicated).
// h1/h2 halves exchanged via global xbufs + epoch flags (2 handshakes/stage);
// partner half DMA'd into LDS via global_load_lds. L2/L3 K-order rotated by
// 16h so own-half A-columns are consumed first (DMA slack ~16 chunks).
// Partner = bid^8 (same-XCD under bid%8 mapping; agent fences keep it
// correct regardless). Grid=256=#CUs, LDS>80KB -> 1 block/CU, all resident.
// ---------------------------------------------------------------------------
__global__ __launch_bounds__(512, 2) void ode_k(
    const void* __restrict__ fp_raw,
    const __hip_bfloat16* __restrict__ Wp0,
    const __hip_bfloat16* __restrict__ Wp1,
    const float* __restrict__ bf1, const float* __restrict__ bf2,
    const float* __restrict__ bf3, const float* __restrict__ dts,
    const int* __restrict__ flags, __hip_bfloat16* __restrict__ xh1,
    __hip_bfloat16* __restrict__ xh2, int* __restrict__ xflag,
    void* __restrict__ out) {
  __shared__ __hip_bfloat16 uA[16 * LDU];       //  8.3 KB
  __shared__ __hip_bfloat16 h1s[16 * LDH];      // 32.3 KB
  __shared__ __hip_bfloat16 h2s[16 * LDH];      // 32.3 KB
  __shared__ float lds_guard[2048];             //  8 KB -> >80KB: 1 block/CU

  const int tid = threadIdx.x;
  const int wave = tid >> 6, lane = tid & 63;
  const int l16 = lane & 15, quad = lane >> 4;
  const int bid = blockIdx.x;
  const int h = (bid >> 3) & 1;                 // half within pair
  const int pair = ((bid >> 4) << 3) + (bid & 7);
  const int m0 = pair * 16;
  const int kh = h << 4;                        // K-rotation (16h) for L2/L3
  const int rb = quad * 4;
  const int ofl = flags[0];
  if (ofl == 31337)
    ((volatile float*)lds_guard)[tid & 2047] = 1.f;

  const __hip_bfloat16* Wall = h ? Wp1 : Wp0;
  const char* gw = (const char*)Wall + wave * 2048 + (size_t)lane * 16;

  __hip_bfloat16* xh1_me = xh1 + (size_t)bid * 8192;
  __hip_bfloat16* xh2_me = xh2 + (size_t)bid * 8192;
  const char* xh1_pt = (const char*)(xh1 + (size_t)(bid ^ 8) * 8192);
  const char* xh2_pt = (const char*)(xh2 + (size_t)(bid ^ 8) * 8192);
  int* xfl_me = xflag + bid * 16;
  int* xfl_pt = xflag + (bid ^ 8) * 16;
  const int dstoff = (1 - h) * 1024;            // partner cols byte offset

  bf16x8 rb0[8], rb1[8];                        // 8-slot register ring

  #define BSTEP(c_, a_, acc0_, acc1_)                                     \
    do {                                                                  \
      VMW();                                                              \
      acc0_ = MFMA16(a_, rb0[(c_) & 7], acc0_);                           \
      acc1_ = MFMA16(a_, rb1[(c_) & 7], acc1_);                           \
      SB0();                                                              \
      { int tc_ = (c_) + 7; if (tc_ >= NCHK) tc_ -= NCHK;                 \
        ld2(rb0[((c_) + 7) & 7], rb1[((c_) + 7) & 7],                     \
            gw + (size_t)tc_ * CHKB); }                                   \
    } while (0)

  // epoch handshake + partner-half DMA into LDS (rows 2w, 2w+1 per wave)
  auto xchg = [&](int ep, const char* xb_pt, char* ldsb) {
    SB0();
    __threadfence();                     // release: drain stores, wbl2
    __syncthreads();
    if (tid == 0) {
      __hip_atomic_store(xfl_me, ep, __ATOMIC_RELEASE,
                         __HIP_MEMORY_SCOPE_AGENT);
      while (__hip_atomic_load(xfl_pt, __ATOMIC_ACQUIRE,
                               __HIP_MEMORY_SCOPE_AGENT) < ep)
        __builtin_amdgcn_s_sleep(8);
    }
    __syncthreads();
    __threadfence();                     // acquire: invalidate L1
    const int row = 2 * wave;
    gld16(xb_pt + row * 1024 + (size_t)lane * 16,
          ldsb + row * (LDH * 2) + dstoff);
    gld16(xb_pt + (row + 1) * 1024 + (size_t)lane * 16,
          ldsb + (row + 1) * (LDH * 2) + dstoff);
    SB0();
  };

  // bias registers: L1/L2 cols = h*512 + wave*64 + nt*16 + l16 (nt<4)
  float b1r[4], b2r[4], b3r[2];
  #pragma unroll
  for (int nt = 0; nt < 4; nt++) {
    const int cg = h * 512 + wave * 64 + nt * 16 + l16;
    b1r[nt] = bf1[cg];
    b2r[nt] = bf2[cg];
  }
  #pragma unroll
  for (int nt = 0; nt < 2; nt++) b3r[nt] = bf3[wave * 32 + nt * 16 + l16];

  // RK4 state (full d range; duplicated across the pair)
  float yreg[2][4], ab[2][4];
  #pragma unroll
  for (int nt = 0; nt < 2; nt++) {
    const int d = wave * 32 + nt * 16 + l16;
    #pragma unroll
    for (int r = 0; r < 4; r++) {
      const int m = m0 + rb + r;
      const size_t si = (size_t)m * D_ + d;
      const float v = ofl ? ((const float*)fp_raw)[si]
                          : __bfloat162float(((const __hip_bfloat16*)fp_raw)[si]);
      yreg[nt][r] = v;
      ab[nt][r] = 0.f;
      uA[(rb + r) * LDU + d] = __float2bfloat16(v);
      if (nt == h)   // pair partner stores the other half
        store_out(out, ((size_t)m * T_) * D_ + d, v, ofl);
    }
  }
  // prime the register ring: chunks 0..6 in flight
  #pragma unroll
  for (int c = 0; c < 7; ++c)
    ld2(rb0[c], rb1[c], gw + (size_t)c * CHKB);
  LBAR();

  int ep = 1;
  #pragma unroll 1
  for (int t = 0; t < T_ - 1; ++t) {
    const float dtv = dts[t];
    #pragma unroll 1
    for (int st4 = 0; st4 < 4; ++st4) {
      // ---- L1: own half of h1 = tanh(u @ W1 + b1), K=256, chunks 0..15 ----
      {
        f32x4 acc[4];
        #pragma unroll
        for (int i = 0; i < 4; i++) acc[i] = f32x4{0.f, 0.f, 0.f, 0.f};
        bf16x8 aF = *(const bf16x8*)&uA[l16 * LDU + quad * 8];
        #pragma unroll
        for (int kk = 0; kk < 8; ++kk) {
          const int kn = (kk + 1 < 8) ? (kk + 1) : 0;
          const bf16x8 aN =
              *(const bf16x8*)&uA[l16 * LDU + kn * 32 + quad * 8];
          BSTEP(2 * kk,     aF, acc[0], acc[1]);
          BSTEP(2 * kk + 1, aF, acc[2], acc[3]);
          aF = aN;
        }
        #pragma unroll
        for (int nt = 0; nt < 4; nt++) {
          const int cL = wave * 64 + nt * 16 + l16;
          #pragma unroll
          for (int r = 0; r < 4; r++) {
            const __hip_bfloat16 hb =
                __float2bfloat16(fast_tanh(acc[nt][r] + b1r[nt]));
            h1s[(rb + r) * LDH + h * 512 + cL] = hb;
            xh1_me[(rb + r) * 512 + cL] = hb;
          }
        }
      }
      xchg(ep, xh1_pt, (char*)h1s); ++ep;
      // ---- L2: own half of h2, K=1024, chunks 16..79, kk=(ck+16h)%32 ----
      {
        f32x4 acc[4];
        #pragma unroll
        for (int i = 0; i < 4; i++) acc[i] = f32x4{0.f, 0.f, 0.f, 0.f};
        bf16x8 aF = *(const bf16x8*)&h1s[l16 * LDH + kh * 32 + quad * 8];
        #pragma unroll 1
        for (int g = 0; g < 8; ++g) {            // 8 chunks per g
          const int cb = 16 + 8 * g;
          #pragma unroll
          for (int q = 0; q < 4; ++q) {
            const int ckn = 4 * g + q + 1;
            int kkn = ((ckn < 32) ? ckn : 0) + kh;
            if (kkn >= 32) kkn -= 32;
            const bf16x8 aN =
                *(const bf16x8*)&h1s[l16 * LDH + kkn * 32 + quad * 8];
            BSTEP(cb + 2 * q,     aF, acc[0], acc[1]);
            BSTEP(cb + 2 * q + 1, aF, acc[2], acc[3]);
            aF = aN;
          }
        }
        #pragma unroll
        for (int nt = 0; nt < 4; nt++) {
          const int cL = wave * 64 + nt * 16 + l16;
          #pragma unroll
          for (int r = 0; r < 4; r++) {
            const __hip_bfloat16 hb =
                __float2bfloat16(fast_tanh(acc[nt][r] + b2r[nt]));
            h2s[(rb + r) * LDH + h * 512 + cL] = hb;
            xh2_me[(rb + r) * 512 + cL] = hb;
          }
        }
      }
      xchg(ep, xh2_pt, (char*)h2s); ++ep;
      // ---- L3: FULL k = h2 @ W3 + b3, chunks 80..111, kk=(ck+16h)%32 ----
      {
        f32x4 k0 = f32x4{0.f, 0.f, 0.f, 0.f};
        f32x4 k1 = f32x4{0.f, 0.f, 0.f, 0.f};
        bf16x8 aF = *(const bf16x8*)&h2s[l16 * LDH + kh * 32 + quad * 8];
        #pragma unroll 1
        for (int g = 0; g < 4; ++g) {            // 8 chunks per g
          const int cb = 80 + 8 * g;
          #pragma unroll
          for (int i = 0; i < 8; ++i) {
            const int ckn = 8 * g + i + 1;
            int kkn = ((ckn < 32) ? ckn : 0) + kh;
            if (kkn >= 32) kkn -= 32;
            const bf16x8 aN =
                *(const bf16x8*)&h2s[l16 * LDH + kkn * 32 + quad * 8];
            BSTEP(cb + i, aF, k0, k1);
            aF = aN;
          }
        }
        // RK4 bookkeeping (full d; identical in both pair halves)
        #pragma unroll
        for (int nt = 0; nt < 2; nt++) {
          const int d = wave * 32 + nt * 16 + l16;
          const f32x4 kacc = nt ? k1 : k0;
          #pragma unroll
          for (int r = 0; r < 4; r++) {
            const float kv = kacc[r] + b3r[nt];
            float uv;
            if (st4 == 0) {
              ab[nt][r] = kv;            uv = yreg[nt][r] + 0.5f * dtv * kv;
            } else if (st4 == 1) {
              ab[nt][r] += 2.f * kv;     uv = yreg[nt][r] + 0.5f * dtv * kv;
            } else if (st4 == 2) {
              ab[nt][r] += 2.f * kv;     uv = yreg[nt][r] + dtv * kv;
            } else {
              const float yn =
                  yreg[nt][r] + (dtv * (1.f / 6.f)) * (ab[nt][r] + kv);
              yreg[nt][r] = yn;
              uv = yn;
              if (nt == h)
                store_out(out,
                          ((size_t)(m0 + rb + r) * T_ + (t + 1)) * D_ + d,
                          yn, ofl);
            }
            uA[(rb + r) * LDU + d] = __float2bfloat16(uv);
          }
        }
      }
      LBAR();
    }
  }
  asm volatile("s_waitcnt vmcnt(0)" ::: "memory");
  #undef BSTEP
}

// ---------------------------------------------------------------------------
extern "C" void kernel_launch(void* const* d_in, const int* in_sizes, int n_in,
                              void* d_out, int out_size, void* d_ws, size_t ws_size,
                              hipStream_t stream) {
  const void* fp   = d_in[0];
  const void* tarr = d_in[1];
  const void* W1   = d_in[2];
  const void* b1   = d_in[3];
  const void* W2   = d_in[4];
  const void* b2   = d_in[5];
  const void* W3   = d_in[6];
  const void* b3   = d_in[7];

  // workspace carve (~14.6 MB), all 16B-aligned
  char* ws = (char*)d_ws;
  __hip_bfloat16* Wp0 = (__hip_bfloat16*)ws; ws += (size_t)NCHK * CHKB;  // 1.75MB
  __hip_bfloat16* Wp1 = (__hip_bfloat16*)ws; ws += (size_t)NCHK * CHKB;  // 1.75MB
  __hip_bfloat16* W1t = (__hip_bfloat16*)ws; ws += (size_t)H_ * D_ * 2;
  __hip_bfloat16* W2t = (__hip_bfloat16*)ws; ws += (size_t)H_ * H_ * 2;
  __hip_bfloat16* W3t = (__hip_bfloat16*)ws; ws += (size_t)D_ * H_ * 2;
  __hip_bfloat16* xh1 = (__hip_bfloat16*)ws; ws += (size_t)256 * 8192 * 2; // 4MB
  __hip_bfloat16* xh2 = (__hip_bfloat16*)ws; ws += (size_t)256 * 8192 * 2; // 4MB
  float* bf1  = (float*)ws;                  ws += (size_t)H_ * 4;
  float* bf2  = (float*)ws;                  ws += (size_t)H_ * 4;
  float* bf3  = (float*)ws;                  ws += (size_t)D_ * 4;
  float* dts  = (float*)ws;                  ws += 64 * 4;
  int*   flags= (int*)ws;                    ws += 64 * 4;
  int*   xflag= (int*)ws;                    ws += 256 * 16 * 4;          // 16KB

  detect_k<<<1, 64, 0, stream>>>(tarr, W2, dts, flags, d_out, xflag);
  dim3 tb(32, 8);
  transpose_k<<<dim3(H_ / 32, D_ / 32), tb, 0, stream>>>(W1, W1t, D_, H_, flags);
  transpose_k<<<dim3(H_ / 32, H_ / 32), tb, 0, stream>>>(W2, W2t, H_, H_, flags);
  transpose_k<<<dim3(D_ / 32, H_ / 32), tb, 0, stream>>>(W3, W3t, H_, D_, flags);
  prep_bias_k<<<H_ / 256, 256, 0, stream>>>(b1, b2, b3, bf1, bf2, bf3, flags);
  // packed streams: [W1h | W2h | W3] per half; W2/W3 K-rotated by 16h
  pack2_k<<< 64, 256, 0, stream>>>(W1t, Wp0,             256, 4, 0,   0);
  pack2_k<<<256, 256, 0, stream>>>(W2t, Wp0 + 16 * 8192, 1024, 4, 0,   0);
  pack2_k<<<128, 256, 0, stream>>>(W3t, Wp0 + 80 * 8192, 1024, 2, 0,   0);
  pack2_k<<< 64, 256, 0, stream>>>(W1t, Wp1,             256, 4, 512,  0);
  pack2_k<<<256, 256, 0, stream>>>(W2t, Wp1 + 16 * 8192, 1024, 4, 512, 16);
  pack2_k<<<128, 256, 0, stream>>>(W3t, Wp1 + 80 * 8192, 1024, 2, 0,   16);
  ode_k<<<256, 512, 0, stream>>>(fp, Wp0, Wp1, bf1, bf2, bf3, dts, flags,
                                 xh1, xh2, xflag, d_out);
}

// Round 8
// 3704.101 us; speedup vs baseline: 10.9511x; 10.9511x over previous
//
#include <hip/hip_runtime.h>
#include <hip/hip_bf16.h>

// Problem constants (S,B,D,H,T) = (4,512,256,1024,50)
#define S_ 4
#define B_ 512
#define D_ 256
#define H_ 1024
#define T_ 50
#define M_ (S_*B_)   // 2048 rows total

#define LDH (H_ + 8)   // padded LDS row stride for h1/h2 (bf16 elems)
#define LDU (D_ + 8)   // padded LDS row stride for u

// Streams of 16KB chunks:
//   FULL (round-6): 192 chunks = 3MB   [W1:0-31 | W2:32-159 | W3:160-191]
//   SPLIT half:     112 chunks = 1.75MB[W1h:0-15 | W2h:16-79 | W3:80-111]
#define NCF 192
#define NCS 112
#define CHKB 16384
#define MAGICV 0x3C96A5E1

typedef __attribute__((ext_vector_type(8))) __bf16 bf16x8;
typedef __attribute__((ext_vector_type(4))) float  f32x4;

#define MFMA16(a, b, c) __builtin_amdgcn_mfma_f32_16x16x32_bf16(a, b, c, 0, 0, 0)
#define SB0() __builtin_amdgcn_sched_barrier(0)
#define VMW() do { asm volatile("s_waitcnt vmcnt(12)" ::: "memory"); SB0(); } while (0)
// layer barrier WITHOUT vmcnt drain
#define LBAR() do { SB0(); asm volatile("s_waitcnt lgkmcnt(0)" ::: "memory"); \
                    __builtin_amdgcn_s_barrier(); SB0(); } while (0)

// compile-time-folding counted waits for ring drain tails
__device__ __forceinline__ void vmw_n(int n) {
  switch (n) {
    case 12: asm volatile("s_waitcnt vmcnt(12)" ::: "memory"); break;
    case 10: asm volatile("s_waitcnt vmcnt(10)" ::: "memory"); break;
    case 8:  asm volatile("s_waitcnt vmcnt(8)"  ::: "memory"); break;
    case 6:  asm volatile("s_waitcnt vmcnt(6)"  ::: "memory"); break;
    case 4:  asm volatile("s_waitcnt vmcnt(4)"  ::: "memory"); break;
    case 2:  asm volatile("s_waitcnt vmcnt(2)"  ::: "memory"); break;
    default: asm volatile("s_waitcnt vmcnt(0)"  ::: "memory"); break;
  }
  SB0();
}

// Two B-fragments (one chunk's per-wave slice halves) global -> VGPR.
__device__ __forceinline__ void ld2(bf16x8& r0, bf16x8& r1, const void* p) {
  asm volatile("global_load_dwordx4 %0, %2, off\n\t"
               "global_load_dwordx4 %1, %2, off offset:1024"
               : "=&v"(r0), "=&v"(r1) : "v"(p) : "memory");
}

// async global->LDS with sc0 (L1 bypass) for partner-half DMA
__device__ __forceinline__ void gld16c(const void* g, void* l) {
  __builtin_amdgcn_global_load_lds(
      (const __attribute__((address_space(1))) void*)g,
      (__attribute__((address_space(3))) void*)l, 16, 0, 1 /*sc0*/);
}

__device__ __forceinline__ float fast_tanh(float x) {
  const float e = __expf(2.f * x);
  return 1.f - 2.f / (e + 1.f);
}

__device__ __forceinline__ void store_out(void* out, size_t off, float v,
                                          int ofl) {
  if (ofl) {
    __builtin_nontemporal_store(v, (float*)out + off);
  } else {
    const unsigned short u =
        __builtin_bit_cast(unsigned short, __float2bfloat16(v));
    __builtin_nontemporal_store(u, (unsigned short*)out + off);
  }
}

// ---------------------------------------------------------------------------
// dtype detection + dt table + reg_state zeros + flag/probe zeroing
// ---------------------------------------------------------------------------
__global__ void detect_k(const void* t_raw, const void* w2_raw,
                         float* dts, int* flags, void* out, int* xflag) {
  __shared__ int cnt;
  const int l = threadIdx.x;           // 64 threads, 1 block
  if (l == 0) cnt = 0;
  __syncthreads();
  const unsigned short* u = (const unsigned short*)w2_raw;
  int c = 0;
  #pragma unroll
  for (int j = 0; j < 4; ++j) {
    const unsigned short v = u[l * 4 + j];
    const unsigned e = (v >> 7) & 0xFF;
    if (e >= 128) c++;
  }
  atomicAdd(&cnt, c);
  __syncthreads();
  const unsigned tw0 = *(const unsigned*)t_raw;
  const int t_is_f32 = (tw0 == 0u) ? 1 : 0;
  const int w_is_f32 = (cnt > 16) ? 1 : 0;
  if (l == 0) { flags[0] = w_is_f32; flags[1] = t_is_f32; }
  for (int i = l; i < 256 * 16; i += 64) xflag[i] = 0;
  if (l < T_ - 1) {
    float t0, t1;
    if (t_is_f32) {
      const float* tf = (const float*)t_raw;
      t0 = tf[l]; t1 = tf[l + 1];
    } else {
      const __hip_bfloat16* tb = (const __hip_bfloat16*)t_raw;
      t0 = __bfloat162float(tb[l]); t1 = __bfloat162float(tb[l + 1]);
    }
    dts[l] = t1 - t0;
  }
  if (l < S_) {
    const size_t ro = (size_t)M_ * T_ * D_ + l;
    if (w_is_f32) ((float*)out)[ro] = 0.f;
    else          ((__hip_bfloat16*)out)[ro] = __float2bfloat16(0.f);
  }
}

// ---------------------------------------------------------------------------
__global__ void transpose_k(const void* __restrict__ src,
                            __hip_bfloat16* __restrict__ dst, int K, int N,
                            const int* __restrict__ flags) {
  __shared__ __hip_bfloat16 tile[32][33];
  const int f32 = flags[0];
  const int tx = threadIdx.x, ty = threadIdx.y;
  const int nb = blockIdx.x * 32, kb = blockIdx.y * 32;
  #pragma unroll
  for (int j = 0; j < 32; j += 8) {
    const size_t si = (size_t)(kb + ty + j) * N + nb + tx;
    tile[ty + j][tx] = f32 ? __float2bfloat16(((const float*)src)[si])
                           : ((const __hip_bfloat16*)src)[si];
  }
  __syncthreads();
  #pragma unroll
  for (int j = 0; j < 32; j += 8)
    dst[(size_t)(nb + ty + j) * K + kb + tx] = tile[tx][ty + j];
}

// ---------------------------------------------------------------------------
__global__ void prep_bias_k(const void* b1r, const void* b2r, const void* b3r,
                            float* bf1, float* bf2, float* bf3,
                            const int* flags) {
  const int i = blockIdx.x * 256 + threadIdx.x;
  const int f32 = flags[0];
  bf1[i] = f32 ? ((const float*)b1r)[i]
               : __bfloat162float(((const __hip_bfloat16*)b1r)[i]);
  bf2[i] = f32 ? ((const float*)b2r)[i]
               : __bfloat162float(((const __hip_bfloat16*)b2r)[i]);
  if (i < D_)
    bf3[i] = f32 ? ((const float*)b3r)[i]
                 : __bfloat162float(((const __hip_bfloat16*)b3r)[i]);
}

// ---------------------------------------------------------------------------
// FULL-stream pack (round-6): TPW==8 (L1/L2) or 2 (L3), wave-private slices.
// ---------------------------------------------------------------------------
__global__ void pack_k(const __hip_bfloat16* __restrict__ Wt,
                       __hip_bfloat16* __restrict__ P, int K, int TPW) {
  const int frag = blockIdx.x * 256 + threadIdx.x;
  const int lane = frag & 63;
  const int c    = frag >> 10;
  const int q    = frag & 1023;
  const int w    = q >> 7;
  const int ntl  = (q >> 6) & 1;
  int kk, nt;
  if (TPW == 8) { kk = c >> 2; nt = (c & 3) * 2 + ntl; }
  else          { kk = c;      nt = ntl; }
  const int n  = (w * TPW + nt) * 16 + (lane & 15);
  const int ko = kk * 32 + (lane >> 4) * 8;
  *(bf16x8*)&P[(size_t)frag * 8] = *(const bf16x8*)&Wt[(size_t)n * K + ko];
}

// ---------------------------------------------------------------------------
// SPLIT-stream pack (round-7): column offset coff, K-rotation krot.
// TPW==4 (L1h/L2h) or 2 (L3 full).
// ---------------------------------------------------------------------------
__global__ void pack2_k(const __hip_bfloat16* __restrict__ Wt,
                        __hip_bfloat16* __restrict__ P, int K, int TPW,
                        int coff, int krot) {
  const int frag = blockIdx.x * 256 + threadIdx.x;
  const int lane = frag & 63;
  const int c    = frag >> 10;
  const int q    = frag & 1023;
  const int w    = q >> 7;
  const int ntl  = (q >> 6) & 1;
  const int KT   = K >> 5;
  int kk0, nt;
  if (TPW == 4) { kk0 = c >> 1; nt = (c & 1) * 2 + ntl; }
  else          { kk0 = c;      nt = ntl; }
  int kk = kk0 + krot; if (kk >= KT) kk -= KT;
  const int n  = coff + (w * TPW + nt) * 16 + (lane & 15);
  const int ko = kk * 32 + (lane >> 4) * 8;
  *(bf16x8*)&P[(size_t)frag * 8] = *(const bf16x8*)&Wt[(size_t)n * K + ko];
}

// ---------------------------------------------------------------------------
// Persistent ODE kernel: 256 blocks (128 pairs), 512 threads, 1 block/CU.
// One-time software probe decides per-pair: SPLIT (same-L2 light sync,
// 1.75MB/stage stream) or FULL (round-6 path, 3MB/stage, no sync).
// ---------------------------------------------------------------------------
__global__ __launch_bounds__(512, 2) void ode_k(
    const void* __restrict__ fp_raw,
    const __hip_bfloat16* __restrict__ Wfull,
    const __hip_bfloat16* __restrict__ Wp0,
    const __hip_bfloat16* __restrict__ Wp1,
    const float* __restrict__ bf1, const float* __restrict__ bf2,
    const float* __restrict__ bf3, const float* __restrict__ dts,
    const int* __restrict__ flags, __hip_bfloat16* __restrict__ xh,
    int* __restrict__ xflag, void* __restrict__ out) {
  __shared__ __hip_bfloat16 uA[16 * LDU];       //  8.3 KB
  __shared__ __hip_bfloat16 h1s[16 * LDH];      // 32.3 KB
  __shared__ __hip_bfloat16 h2s[16 * LDH];      // 32.3 KB
  __shared__ float lds_guard[2048];             //  8 KB -> >80KB: 1 block/CU

  const int tid = threadIdx.x;
  const int wave = tid >> 6, lane = tid & 63;
  const int l16 = lane & 15, quad = lane >> 4;
  const int bid = blockIdx.x;
  const int h = (bid >> 3) & 1;
  const int pair = ((bid >> 4) << 3) + (bid & 7);
  const int m0 = pair * 16;
  const int kh = h << 4;                        // K-rotation for split L2/L3
  const int rb = quad * 4;
  const int ofl = flags[0];
  if (ofl == 31337)
    ((volatile float*)lds_guard)[tid & 2047] = 1.f;

  int* xslot_me = xflag + bid * 16;             // [0]=flag [4]=probeF [8]=probeD
  int* xslot_pt = xflag + (bid ^ 8) * 16;
  __hip_bfloat16* xh_me = xh + (size_t)bid * 8192;
  const char* xh_pt = (const char*)(xh + (size_t)(bid ^ 8) * 8192);
  const int dstoff = (1 - h) * 1024;            // partner cols byte offset

  bf16x8 rb0[8], rb1[8];                        // 8-slot register ring

  // steady step: wait(12); 2 MFMAs on slot c&7; refill slot (c+7)&7.
  #define BSTEPX(c_, a_, x_, y_, NC_)                                     \
    do {                                                                  \
      VMW();                                                              \
      x_ = MFMA16(a_, rb0[(c_) & 7], x_);                                 \
      y_ = MFMA16(a_, rb1[(c_) & 7], y_);                                 \
      SB0();                                                              \
      { int tc_ = (c_) + 7; if (tc_ >= (NC_)) tc_ -= (NC_);               \
        ld2(rb0[((c_) + 7) & 7], rb1[((c_) + 7) & 7],                     \
            gw + (size_t)tc_ * CHKB); }                                   \
    } while (0)
  // tail step: counted wait w_, no refill (ring drains to 0)
  #define BSTEPT(c_, a_, x_, y_, w_)                                      \
    do {                                                                  \
      vmw_n(w_);                                                          \
      x_ = MFMA16(a_, rb0[(c_) & 7], x_);                                 \
      y_ = MFMA16(a_, rb1[(c_) & 7], y_);                                 \
      SB0();                                                              \
    } while (0)

  // RK4 state (full d range; duplicated across the pair)
  float yreg[2][4], ab[2][4];
  #pragma unroll
  for (int nt = 0; nt < 2; nt++) {
    const int d = wave * 32 + nt * 16 + l16;
    #pragma unroll
    for (int r = 0; r < 4; r++) {
      const int m = m0 + rb + r;
      const size_t si = (size_t)m * D_ + d;
      const float v = ofl ? ((const float*)fp_raw)[si]
                          : __bfloat162float(((const __hip_bfloat16*)fp_raw)[si]);
      yreg[nt][r] = v;
      ab[nt][r] = 0.f;
      uA[(rb + r) * LDU + d] = __float2bfloat16(v);
      if (nt == h)
        store_out(out, ((size_t)m * T_) * D_ + d, v, ofl);
    }
  }
  float b3r[2];
  #pragma unroll
  for (int nt = 0; nt < 2; nt++) b3r[nt] = bf3[wave * 32 + nt * 16 + l16];

  // ---- one-time same-L2 probe: plain store + sc0-only read round trip ----
  int mode_split;
  {
    if (tid == 0) {
      int* pD = xslot_me + 8; int* pF = xslot_me + 4;
      asm volatile("global_store_dword %0, %1, off\n\t"
                   "s_waitcnt vmcnt(0)\n\t"
                   "global_store_dword %2, %3, off sc0 sc1\n\t"
                   "s_waitcnt vmcnt(0)"
                   :: "v"(pD), "v"((int)MAGICV), "v"(pF), "v"(1) : "memory");
    }
    const int* pFt = xslot_pt + 4; const int* pDt = xslot_pt + 8;
    int pv;
    for (;;) {
      asm volatile("global_load_dword %0, %1, off sc0 sc1\n\t"
                   "s_waitcnt vmcnt(0)" : "=v"(pv) : "v"(pFt) : "memory");
      if (pv != 0) break;
      __builtin_amdgcn_s_sleep(2);
    }
    int dv;
    asm volatile("global_load_dword %0, %1, off sc0\n\t"
                 "s_waitcnt vmcnt(0)" : "=v"(dv) : "v"(pDt) : "memory");
    mode_split = (dv == (int)MAGICV) ? 1 : 0;
  }
  __syncthreads();

  if (mode_split) {
    // ===================== SPLIT PATH (1.75MB/stage) ======================
    const char* gw = (const char*)(h ? Wp1 : Wp0) + wave * 2048 +
                     (size_t)lane * 16;
    float b1r[4], b2r[4];
    #pragma unroll
    for (int nt = 0; nt < 4; nt++) {
      const int cg = h * 512 + wave * 64 + nt * 16 + l16;
      b1r[nt] = bf1[cg];
      b2r[nt] = bf2[cg];
    }
    #pragma unroll
    for (int c = 0; c < 7; ++c)
      ld2(rb0[c], rb1[c], gw + (size_t)c * CHKB);
    LBAR();

    int ep = 1;
    // exchange: ring is empty here; drain own stores; flag; burst next
    // segment; SCALAR poll (vmcnt untouched); DMA partner half into LDS.
    auto xchg = [&](int ep_, int burst0, char* ldsdst) {
      asm volatile("s_waitcnt vmcnt(0)" ::: "memory");
      __syncthreads();
      if (tid == 0) {
        asm volatile("global_store_dword %0, %1, off sc0"
                     :: "v"(xslot_me), "v"(ep_) : "memory");
      }
      #pragma unroll
      for (int i = 0; i < 7; ++i)
        ld2(rb0[i], rb1[i], gw + (size_t)(burst0 + i) * CHKB);
      {
        int v;
        for (;;) {
          asm volatile("s_dcache_inv\n\t"
                       "s_load_dword %0, %1, 0\n\t"
                       "s_waitcnt lgkmcnt(0)"
                       : "=s"(v) : "s"((const int*)xslot_pt));
          if (v >= ep_) break;
          __builtin_amdgcn_s_sleep(1);
        }
      }
      const int row = 2 * wave;
      gld16c(xh_pt + row * 1024 + (size_t)lane * 16,
             ldsdst + row * (LDH * 2) + dstoff);
      gld16c(xh_pt + (row + 1) * 1024 + (size_t)lane * 16,
             ldsdst + (row + 1) * (LDH * 2) + dstoff);
      SB0();
    };

    #pragma unroll 1
    for (int t = 0; t < T_ - 1; ++t) {
      const float dtv = dts[t];
      #pragma unroll 1
      for (int st4 = 0; st4 < 4; ++st4) {
        // ---- L1h: own 512 cols of h1, K=256, chunks 0..15 (drains) ----
        {
          f32x4 acc[4];
          #pragma unroll
          for (int i = 0; i < 4; i++) acc[i] = f32x4{0.f, 0.f, 0.f, 0.f};
          #pragma unroll
          for (int kk = 0; kk < 8; ++kk) {
            const bf16x8 aF =
                *(const bf16x8*)&uA[l16 * LDU + kk * 32 + quad * 8];
            const int p0 = 2 * kk, p1 = 2 * kk + 1;
            if (p0 <= 8) BSTEPX(p0, aF, acc[0], acc[1], NCS);
            else BSTEPT(p0, aF, acc[0], acc[1],
                        (2 * (15 - p0) > 12) ? 12 : 2 * (15 - p0));
            if (p1 <= 8) BSTEPX(p1, aF, acc[2], acc[3], NCS);
            else BSTEPT(p1, aF, acc[2], acc[3],
                        (2 * (15 - p1) > 12) ? 12 : 2 * (15 - p1));
          }
          #pragma unroll
          for (int nt = 0; nt < 4; nt++) {
            const int cL = wave * 64 + nt * 16 + l16;
            #pragma unroll
            for (int r = 0; r < 4; r++) {
              const __hip_bfloat16 hb =
                  __float2bfloat16(fast_tanh(acc[nt][r] + b1r[nt]));
              h1s[(rb + r) * LDH + h * 512 + cL] = hb;
              xh_me[(rb + r) * 512 + cL] = hb;
            }
          }
        }
        xchg(ep, 16, (char*)h1s); ++ep;
        // ---- L2h: own 512 cols of h2, K=1024, chunks 16..79 (drains) ----
        {
          f32x4 acc[4];
          #pragma unroll
          for (int i = 0; i < 4; i++) acc[i] = f32x4{0.f, 0.f, 0.f, 0.f};
          #pragma unroll 1
          for (int g = 0; g < 7; ++g) {
            const int cb = 16 + 8 * g;
            #pragma unroll
            for (int q = 0; q < 4; ++q) {
              const int kkA = ((4 * g + q) + kh) & 31;
              const bf16x8 aF =
                  *(const bf16x8*)&h1s[l16 * LDH + kkA * 32 + quad * 8];
              BSTEPX(cb + 2 * q,     aF, acc[0], acc[1], NCS);
              BSTEPX(cb + 2 * q + 1, aF, acc[2], acc[3], NCS);
            }
          }
          #pragma unroll
          for (int m = 0; m < 4; ++m) {          // tail p=72..79
            const int kkA = (28 + m + kh) & 31;
            const bf16x8 aF =
                *(const bf16x8*)&h1s[l16 * LDH + kkA * 32 + quad * 8];
            const int p0 = 72 + 2 * m, p1 = p0 + 1;
            if (p0 == 72) BSTEPX(72, aF, acc[0], acc[1], NCS);
            else BSTEPT(p0, aF, acc[0], acc[1],
                        (2 * (79 - p0) > 12) ? 12 : 2 * (79 - p0));
            BSTEPT(p1, aF, acc[2], acc[3],
                   (2 * (79 - p1) > 12) ? 12 : 2 * (79 - p1));
          }
          #pragma unroll
          for (int nt = 0; nt < 4; nt++) {
            const int cL = wave * 64 + nt * 16 + l16;
            #pragma unroll
            for (int r = 0; r < 4; r++) {
              const __hip_bfloat16 hb =
                  __float2bfloat16(fast_tanh(acc[nt][r] + b2r[nt]));
              h2s[(rb + r) * LDH + h * 512 + cL] = hb;
              xh_me[(rb + r) * 512 + cL] = hb;
            }
          }
        }
        xchg(ep, 80, (char*)h2s); ++ep;
        // ---- L3: FULL k, K=1024, chunks 80..111 (wraps into next L1) ----
        {
          f32x4 k0 = f32x4{0.f, 0.f, 0.f, 0.f};
          f32x4 k1 = f32x4{0.f, 0.f, 0.f, 0.f};
          #pragma unroll 1
          for (int g = 0; g < 4; ++g) {
            const int cb = 80 + 8 * g;
            #pragma unroll
            for (int i = 0; i < 8; ++i) {
              const int kkA = ((8 * g + i) + kh) & 31;
              const bf16x8 aF =
                  *(const bf16x8*)&h2s[l16 * LDH + kkA * 32 + quad * 8];
              BSTEPX(cb + i, aF, k0, k1, NCS);
            }
          }
          #pragma unroll
          for (int nt = 0; nt < 2; nt++) {
            const int d = wave * 32 + nt * 16 + l16;
            const f32x4 kacc = nt ? k1 : k0;
            #pragma unroll
            for (int r = 0; r < 4; r++) {
              const float kv = kacc[r] + b3r[nt];
              float uv;
              if (st4 == 0) {
                ab[nt][r] = kv;           uv = yreg[nt][r] + 0.5f * dtv * kv;
              } else if (st4 == 1) {
                ab[nt][r] += 2.f * kv;    uv = yreg[nt][r] + 0.5f * dtv * kv;
              } else if (st4 == 2) {
                ab[nt][r] += 2.f * kv;    uv = yreg[nt][r] + dtv * kv;
              } else {
                const float yn =
                    yreg[nt][r] + (dtv * (1.f / 6.f)) * (ab[nt][r] + kv);
                yreg[nt][r] = yn;
                uv = yn;
                if (nt == h)
                  store_out(out,
                            ((size_t)(m0 + rb + r) * T_ + (t + 1)) * D_ + d,
                            yn, ofl);
              }
              uA[(rb + r) * LDU + d] = __float2bfloat16(uv);
            }
          }
        }
        LBAR();
      }
    }
  } else {
    // ===================== FULL PATH (round-6, 3MB/stage) =================
    const char* gw = (const char*)Wfull + wave * 2048 + (size_t)lane * 16;
    float b1r8[8], b2r8[8];
    #pragma unroll
    for (int nt = 0; nt < 8; nt++) {
      b1r8[nt] = bf1[wave * 128 + nt * 16 + l16];
      b2r8[nt] = bf2[wave * 128 + nt * 16 + l16];
    }
    #pragma unroll
    for (int c = 0; c < 7; ++c)
      ld2(rb0[c], rb1[c], gw + (size_t)c * CHKB);
    LBAR();

    #pragma unroll 1
    for (int t = 0; t < T_ - 1; ++t) {
      const float dtv = dts[t];
      #pragma unroll 1
      for (int st4 = 0; st4 < 4; ++st4) {
        // ---- L1: K=256, chunks 0..31 ----
        {
          f32x4 acc[8];
          #pragma unroll
          for (int i = 0; i < 8; i++) acc[i] = f32x4{0.f, 0.f, 0.f, 0.f};
          #pragma unroll
          for (int kk = 0; kk < 8; ++kk) {
            const bf16x8 aF =
                *(const bf16x8*)&uA[l16 * LDU + kk * 32 + quad * 8];
            const int cb = 4 * kk;
            BSTEPX(cb + 0, aF, acc[0], acc[1], NCF);
            BSTEPX(cb + 1, aF, acc[2], acc[3], NCF);
            BSTEPX(cb + 2, aF, acc[4], acc[5], NCF);
            BSTEPX(cb + 3, aF, acc[6], acc[7], NCF);
          }
          #pragma unroll
          for (int nt = 0; nt < 8; nt++) {
            const int col = wave * 128 + nt * 16 + l16;
            #pragma unroll
            for (int r = 0; r < 4; r++)
              h1s[(rb + r) * LDH + col] =
                  __float2bfloat16(fast_tanh(acc[nt][r] + b1r8[nt]));
          }
        }
        LBAR();
        // ---- L2: K=1024, chunks 32..159 ----
        {
          f32x4 acc[8];
          #pragma unroll
          for (int i = 0; i < 8; i++) acc[i] = f32x4{0.f, 0.f, 0.f, 0.f};
          #pragma unroll 1
          for (int kk2 = 0; kk2 < 16; ++kk2) {
            const int cb = 32 + 8 * kk2;
            const bf16x8 aF0 =
                *(const bf16x8*)&h1s[l16 * LDH + (2 * kk2) * 32 + quad * 8];
            BSTEPX(cb + 0, aF0, acc[0], acc[1], NCF);
            BSTEPX(cb + 1, aF0, acc[2], acc[3], NCF);
            BSTEPX(cb + 2, aF0, acc[4], acc[5], NCF);
            BSTEPX(cb + 3, aF0, acc[6], acc[7], NCF);
            const bf16x8 aF1 =
                *(const bf16x8*)&h1s[l16 * LDH + (2 * kk2 + 1) * 32 + quad * 8];
            BSTEPX(cb + 4, aF1, acc[0], acc[1], NCF);
            BSTEPX(cb + 5, aF1, acc[2], acc[3], NCF);
            BSTEPX(cb + 6, aF1, acc[4], acc[5], NCF);
            BSTEPX(cb + 7, aF1, acc[6], acc[7], NCF);
          }
          #pragma unroll
          for (int nt = 0; nt < 8; nt++) {
            const int col = wave * 128 + nt * 16 + l16;
            #pragma unroll
            for (int r = 0; r < 4; r++)
              h2s[(rb + r) * LDH + col] =
                  __float2bfloat16(fast_tanh(acc[nt][r] + b2r8[nt]));
          }
        }
        LBAR();
        // ---- L3: K=1024, chunks 160..191 ----
        {
          f32x4 k0 = f32x4{0.f, 0.f, 0.f, 0.f};
          f32x4 k1 = f32x4{0.f, 0.f, 0.f, 0.f};
          #pragma unroll 1
          for (int g = 0; g < 4; ++g) {
            const int cb = 160 + 8 * g;
            #pragma unroll
            for (int i = 0; i < 8; ++i) {
              const int kk = 8 * g + i;
              const bf16x8 aF =
                  *(const bf16x8*)&h2s[l16 * LDH + kk * 32 + quad * 8];
              BSTEPX(cb + i, aF, k0, k1, NCF);
            }
          }
          #pragma unroll
          for (int nt = 0; nt < 2; nt++) {
            const int d = wave * 32 + nt * 16 + l16;
            const f32x4 kacc = nt ? k1 : k0;
            #pragma unroll
            for (int r = 0; r < 4; r++) {
              const float kv = kacc[r] + b3r[nt];
              float uv;
              if (st4 == 0) {
                ab[nt][r] = kv;           uv = yreg[nt][r] + 0.5f * dtv * kv;
              } else if (st4 == 1) {
                ab[nt][r] += 2.f * kv;    uv = yreg[nt][r] + 0.5f * dtv * kv;
              } else if (st4 == 2) {
                ab[nt][r] += 2.f * kv;    uv = yreg[nt][r] + dtv * kv;
              } else {
                const float yn =
                    yreg[nt][r] + (dtv * (1.f / 6.f)) * (ab[nt][r] + kv);
                yreg[nt][r] = yn;
                uv = yn;
                if (nt == h)
                  store_out(out,
                            ((size_t)(m0 + rb + r) * T_ + (t + 1)) * D_ + d,
                            yn, ofl);
              }
              uA[(rb + r) * LDU + d] = __float2bfloat16(uv);
            }
          }
        }
        LBAR();
      }
    }
  }
  asm volatile("s_waitcnt vmcnt(0)" ::: "memory");  // retire dangling prefetch
  #undef BSTEPX
  #undef BSTEPT
}

// ---------------------------------------------------------------------------
extern "C" void kernel_launch(void* const* d_in, const int* in_sizes, int n_in,
                              void* d_out, int out_size, void* d_ws, size_t ws_size,
                              hipStream_t stream) {
  const void* fp   = d_in[0];
  const void* tarr = d_in[1];
  const void* W1   = d_in[2];
  const void* b1   = d_in[3];
  const void* W2   = d_in[4];
  const void* b2   = d_in[5];
  const void* W3   = d_in[6];
  const void* b3   = d_in[7];

  // workspace carve (~14.2 MB), all 16B-aligned
  char* ws = (char*)d_ws;
  __hip_bfloat16* Wf  = (__hip_bfloat16*)ws; ws += (size_t)NCF * CHKB;   // 3MB
  __hip_bfloat16* Wp0 = (__hip_bfloat16*)ws; ws += (size_t)NCS * CHKB;   // 1.75MB
  __hip_bfloat16* Wp1 = (__hip_bfloat16*)ws; ws += (size_t)NCS * CHKB;   // 1.75MB
  __hip_bfloat16* W1t = (__hip_bfloat16*)ws; ws += (size_t)H_ * D_ * 2;
  __hip_bfloat16* W2t = (__hip_bfloat16*)ws; ws += (size_t)H_ * H_ * 2;
  __hip_bfloat16* W3t = (__hip_bfloat16*)ws; ws += (size_t)D_ * H_ * 2;
  __hip_bfloat16* xh  = (__hip_bfloat16*)ws; ws += (size_t)256 * 8192 * 2; // 4MB
  float* bf1  = (float*)ws;                  ws += (size_t)H_ * 4;
  float* bf2  = (float*)ws;                  ws += (size_t)H_ * 4;
  float* bf3  = (float*)ws;                  ws += (size_t)D_ * 4;
  float* dts  = (float*)ws;                  ws += 64 * 4;
  int*   flags= (int*)ws;                    ws += 64 * 4;
  int*   xflag= (int*)ws;                    ws += 256 * 16 * 4;           // 16KB

  detect_k<<<1, 64, 0, stream>>>(tarr, W2, dts, flags, d_out, xflag);
  dim3 tb(32, 8);
  transpose_k<<<dim3(H_ / 32, D_ / 32), tb, 0, stream>>>(W1, W1t, D_, H_, flags);
  transpose_k<<<dim3(H_ / 32, H_ / 32), tb, 0, stream>>>(W2, W2t, H_, H_, flags);
  transpose_k<<<dim3(D_ / 32, H_ / 32), tb, 0, stream>>>(W3, W3t, H_, D_, flags);
  prep_bias_k<<<H_ / 256, 256, 0, stream>>>(b1, b2, b3, bf1, bf2, bf3, flags);
  // FULL stream [W1|W2|W3]
  pack_k<<<(H_ * D_ / 8) / 256, 256, 0, stream>>>(W1t, Wf, D_, 8);
  pack_k<<<(H_ * H_ / 8) / 256, 256, 0, stream>>>(W2t, Wf + 32 * 8192, H_, 8);
  pack_k<<<(D_ * H_ / 8) / 256, 256, 0, stream>>>(W3t, Wf + 160 * 8192, H_, 2);
  // SPLIT half-streams [W1h|W2h|W3]; W2/W3 K-rotated by 16h
  pack2_k<<< 64, 256, 0, stream>>>(W1t, Wp0,             256,  4, 0,   0);
  pack2_k<<<256, 256, 0, stream>>>(W2t, Wp0 + 16 * 8192, 1024, 4, 0,   0);
  pack2_k<<<128, 256, 0, stream>>>(W3t, Wp0 + 80 * 8192, 1024, 2, 0,   0);
  pack2_k<<< 64, 256, 0, stream>>>(W1t, Wp1,             256,  4, 512, 0);
  pack2_k<<<256, 256, 0, stream>>>(W2t, Wp1 + 16 * 8192, 1024, 4, 512, 16);
  pack2_k<<<128, 256, 0, stream>>>(W3t, Wp1 + 80 * 8192, 1024, 2, 0,   16);
  ode_k<<<256, 512, 0, stream>>>(fp, Wf, Wp0, Wp1, bf1, bf2, bf3, dts, flags,
                                 xh, xflag, d_out);
}